// Round 8
// baseline (898.093 us; speedup 1.0000x reference)
//
#include <hip/hip_runtime.h>
#include <hip/hip_bf16.h>

#define B_ 4
#define N_ 4096
#define C_ 256
#define P_ 1024
#define S_ 64
#define HST 264   // H LDS k-stride (bf16 elems); 528B rows -> 2-way (free) frag reads

typedef __attribute__((ext_vector_type(8))) short short8;
typedef __attribute__((ext_vector_type(4))) float f32x4;
typedef __attribute__((ext_vector_type(2))) float f32x2;

__device__ __forceinline__ float rn_mul(float a, float b){ return __fmul_rn(a,b); }
__device__ __forceinline__ float rn_add(float a, float b){ return __fadd_rn(a,b); }
__device__ __forceinline__ float rn_sub(float a, float b){ return __fsub_rn(a,b); }

__device__ __forceinline__ unsigned short f2bf(float x){ // RNE f32->bf16
  union { float f; unsigned u; } v; v.f = x;
  unsigned r = v.u + 0x7fffu + ((v.u >> 16) & 1u);
  return (unsigned short)(r >> 16);
}

// v_max with a DPP-permuted copy; OOB/disabled lanes contribute 0 (safe: dists >= 0)
#define DPPMAX(m, ctrl) \
  m = fmaxf(m, __int_as_float(__builtin_amdgcn_update_dpp(0, __float_as_int(m), ctrl, 0xF, 0xF, true)))

// ---------------- FPS: one block/batch, 4 waves x 16 pts ----------------
// r7 structure with: (1) VOP3P inline-asm dist update (exact: pk_add/pk_mul are
// RN ops; subtract = add of exactly-negated centroid; left-fold (dx2+dy2)+dz2;
// v_min == jnp.minimum), (2) match-bits computed vs lane-max lm BEFORE the DPP
// chain (winning lane's lm == ms, so jj/ballot semantics identical), (3) float4
// point store for single-b128 winner-coord fetch.
__global__ __launch_bounds__(256, 1) void fps_kernel(const float* __restrict__ xyz,
                                                     float* __restrict__ newXyz)
{
  const int b = blockIdx.x;
  const int t = threadIdx.x;            // 0..255
  const int lane = t & 63, w = t >> 6;  // 4 waves
  __shared__ float4 xl4[N_];            // 64 KB padded point store (b128 fetch)
  __shared__ float4 cand[2][4];
  __shared__ float4 nstage[P_];         // 16 KB centroid staging (flushed once)
  const float* xb = xyz + (size_t)b*N_*3;

  // coalesced load of 16 points/lane into registers, then padded LDS store
  float buf[48];
  #pragma unroll
  for (int i=0;i<12;i++){
    const float4 v = *(const float4*)(xb + t*48 + i*4);
    buf[i*4+0]=v.x; buf[i*4+1]=v.y; buf[i*4+2]=v.z; buf[i*4+3]=v.w;
  }
  f32x2 px[8], py[8], pz[8], dist[8];
  #pragma unroll
  for (int k=0;k<8;k++){
    px[k] = (f32x2){buf[6*k+0], buf[6*k+3]};   // .x = point 2k, .y = point 2k+1
    py[k] = (f32x2){buf[6*k+1], buf[6*k+4]};
    pz[k] = (f32x2){buf[6*k+2], buf[6*k+5]};
    dist[k] = (f32x2){1e10f, 1e10f};
  }
  #pragma unroll
  for (int j=0;j<16;j++)
    xl4[t*16 + j] = make_float4(buf[3*j+0], buf[3*j+1], buf[3*j+2], 0.f);
  __syncthreads();
  float cx, cy, cz;
  { const float4 c0 = xl4[0]; cx = c0.x; cy = c0.y; cz = c0.z; }  // farthest_0 = 0

  for (int it=0; it<P_; ++it){
    if (t == 0) nstage[it] = make_float4(cx, cy, cz, 0.f);   // LDS, not global
    // ---- packed distance update: forced VOP3P, exact RN semantics ----
    const f32x2 ncx = (f32x2){-cx,-cx}, ncy = (f32x2){-cy,-cy}, ncz = (f32x2){-cz,-cz};
    f32x2 nd[8];
    #pragma unroll
    for (int k=0;k<8;k++){
      f32x2 d, tmp;
      asm("v_pk_add_f32 %0, %2, %5\n\t"   // dx = px + (-cx)
          "v_pk_add_f32 %1, %3, %6\n\t"   // dy = py + (-cy)
          "v_pk_mul_f32 %0, %0, %0\n\t"   // dx*dx
          "v_pk_mul_f32 %1, %1, %1\n\t"   // dy*dy
          "v_pk_add_f32 %0, %0, %1\n\t"   // dx2+dy2
          "v_pk_add_f32 %1, %4, %7\n\t"   // dz = pz + (-cz)
          "v_pk_mul_f32 %1, %1, %1\n\t"   // dz*dz
          "v_pk_add_f32 %0, %0, %1"       // d = (dx2+dy2)+dz2
          : "=&v"(d), "=&v"(tmp)
          : "v"(px[k]), "v"(py[k]), "v"(pz[k]), "v"(ncx), "v"(ncy), "v"(ncz));
      nd[k] = __builtin_elementwise_min(dist[k], d);
      dist[k] = nd[k];
    }
    // ---- lane max via exact scalar tree (halves are separate VGPRs, free) ----
    const float e0  = fmaxf(nd[0].x, nd[0].y), e1 = fmaxf(nd[1].x, nd[1].y);
    const float e2  = fmaxf(nd[2].x, nd[2].y), e3 = fmaxf(nd[3].x, nd[3].y);
    const float e4  = fmaxf(nd[4].x, nd[4].y), e5 = fmaxf(nd[5].x, nd[5].y);
    const float e6  = fmaxf(nd[6].x, nd[6].y), e7 = fmaxf(nd[7].x, nd[7].y);
    const float f0  = fmaxf(e0, e1), f1 = fmaxf(e2, e3);
    const float f2  = fmaxf(e4, e5), f3 = fmaxf(e6, e7);
    const float lm  = fmaxf(fmaxf(f0, f1), fmaxf(f2, f3));
    // ---- first-match bits vs lane max (off the post-readlane serial path) ----
    unsigned bits = 0u;
    #pragma unroll
    for (int k=0;k<8;k++){
      bits |= (nd[k].x == lm) ? (1u << (2*k))   : 0u;
      bits |= (nd[k].y == lm) ? (1u << (2*k+1)) : 0u;
    }
    const int jj = __ffs(bits) - 1;                   // first index in lane
    // ---- wave max via DPP (VALU pipe) ----
    float m = lm;
    DPPMAX(m, 0x111);  // row_shr:1
    DPPMAX(m, 0x112);  // row_shr:2
    DPPMAX(m, 0x114);  // row_shr:4
    DPPMAX(m, 0x118);  // row_shr:8
    DPPMAX(m, 0x142);  // row_bcast:15
    DPPMAX(m, 0x143);  // row_bcast:31
    const float ms = __int_as_float(__builtin_amdgcn_readlane(__float_as_int(m), 63));
    const unsigned long long bal = __ballot(lm == ms);
    const int winlane = __ffsll((long long)bal) - 1;  // lowest lane = lowest index
    const int widx = __builtin_amdgcn_readlane(t*16 + jj, winlane);
    const int pb = it & 1;                            // double buffer (skew <= 1 iter)
    if (lane == 0){
      const float4 cp = xl4[widx];                    // one ds_read_b128
      cand[pb][w] = make_float4(ms, cp.x, cp.y, cp.z);
    }
    __syncthreads();
    // ---- keep-first scan over 4 wave candidates (ascending wave id) ----
    const float4 c0 = cand[pb][0], c1 = cand[pb][1], c2 = cand[pb][2], c3 = cand[pb][3];
    float fv = c0.x; cx = c0.y; cy = c0.z; cz = c0.w;
    if (c1.x > fv){ fv = c1.x; cx = c1.y; cy = c1.z; cz = c1.w; }
    if (c2.x > fv){ fv = c2.x; cx = c2.y; cy = c2.z; cz = c2.w; }
    if (c3.x > fv){ fv = c3.x; cx = c3.y; cy = c3.z; cz = c3.w; }
  }
  __syncthreads();
  // flush staged centroids once
  for (int i = t; i < P_; i += 256){
    const float4 v = nstage[i];
    float* nz = newXyz + ((size_t)b*P_ + i)*3;
    nz[0] = v.x; nz[1] = v.y; nz[2] = v.z;
  }
}

// ---------------- feature transpose (B,C,N) f32 -> (B,N,C) bf16 ----------------
__global__ __launch_bounds__(256) void ftrans_kernel(const float* __restrict__ f,
                                                     unsigned short* __restrict__ ft)
{
  __shared__ float tile[32][33];
  const int b = blockIdx.z;
  const int n0 = blockIdx.x*32, c0 = blockIdx.y*32;
  const int tx = threadIdx.x & 31, ty = threadIdx.x >> 5; // 32x8
  #pragma unroll
  for (int j=0;j<4;j++)
    tile[ty + j*8][tx] = f[((size_t)b*C_ + (size_t)(c0+ty+j*8))*N_ + n0 + tx];
  __syncthreads();
  #pragma unroll
  for (int j=0;j<4;j++)
    ft[((size_t)b*N_ + (size_t)(n0+ty+j*8))*C_ + c0 + tx] = f2bf(tile[tx][ty + j*8]);
}

// ---------------- weight prep: bf16, features-first permutation, zero pad ----------------
__global__ __launch_bounds__(256) void wprep_kernel(const float* __restrict__ W1,
                                                    const float* __restrict__ W2,
                                                    unsigned short* __restrict__ Wp1,
                                                    unsigned short* __restrict__ Wp2)
{
  const int o = blockIdx.x, t = threadIdx.x;
  Wp1[o*288 + t] = f2bf(W1[o*259 + 3 + t]);
  if (t < 32){
    float v = (t < 3) ? W1[o*259 + t] : 0.f;
    Wp1[o*288 + 256 + t] = f2bf(v);
  }
  Wp2[o*256 + t] = f2bf(W2[o*256 + t]);
}

// ---------------- cylinder query: one wave per (b,p); writes bf16 rot fragments ----------------
__global__ __launch_bounds__(256) void query_kernel(const float* __restrict__ xyz,
                                                    const float* __restrict__ rot,
                                                    const float* __restrict__ newXyz,
                                                    int* __restrict__ sIdx,
                                                    unsigned short* __restrict__ sRotPk)
{
  const int lane = threadIdx.x & 63;
  const int bp = blockIdx.x * 4 + (threadIdx.x >> 6);
  const int b = bp >> 10;
  const float* xb = xyz + (size_t)b*N_*3;
  const float* r9 = rot + (size_t)bp*9;
  const float R0=r9[0],R1=r9[1],R2=r9[2],R3=r9[3],R4=r9[4],R5=r9[5],R6=r9[6],R7=r9[7],R8=r9[8];
  const float nx=newXyz[bp*3+0], ny=newXyz[bp*3+1], nz=newXyz[bp*3+2];
  const float thr = R2;   // replicate the reference's r2-shadowing bug
  int* oI = sIdx + (size_t)bp*S_;
  unsigned short* oR = sRotPk + (size_t)bp*S_*8;
  int filled = 0;
  float p0r0=0.f, p0r1=0.f, p0r2=0.f;
  for (int base = 0; base < N_; base += 64){
    const int n = base + lane;
    const float dx = rn_sub(xb[n*3+0], nx);
    const float dy = rn_sub(xb[n*3+1], ny);
    const float dz = rn_sub(xb[n*3+2], nz);
    const float r0 = rn_add(rn_add(rn_mul(dx,R0), rn_mul(dy,R3)), rn_mul(dz,R6));
    const float r1 = rn_add(rn_add(rn_mul(dx,R1), rn_mul(dy,R4)), rn_mul(dz,R7));
    const float r2 = rn_add(rn_add(rn_mul(dx,R2), rn_mul(dy,R5)), rn_mul(dz,R8));
    if (base == 0){
      p0r0 = __shfl(r0, 0, 64); p0r1 = __shfl(r1, 0, 64); p0r2 = __shfl(r2, 0, 64);
    }
    const float d2 = rn_add(rn_mul(r1,r1), rn_mul(r2,r2));
    const bool m = (d2 < thr) & (r0 > -0.02f) & (r0 < 0.04f);
    const unsigned long long bal = __ballot(m);
    const int before = (int)__popcll(bal & ((1ull << lane) - 1ull));
    const int slot = filled + before;
    if (m && slot < S_){
      oI[slot] = n;
      uint4 u;
      u.x = (unsigned)f2bf(r0) | ((unsigned)f2bf(r1) << 16);
      u.y = (unsigned)f2bf(r2);
      u.z = 0u; u.w = 0u;
      *(uint4*)(oR + slot*8) = u;
    }
    filled += (int)__popcll(bal);
    if (filled >= S_) break;
  }
  if (filled < S_){
    const int slot = filled + lane;
    if (slot < S_){
      oI[slot] = 0;
      uint4 u;
      u.x = (unsigned)f2bf(p0r0) | ((unsigned)f2bf(p0r1) << 16);
      u.y = (unsigned)f2bf(p0r2);
      u.z = 0u; u.w = 0u;
      *(uint4*)(oR + slot*8) = u;
    }
  }
}

// ---------------- MFMA MLP: 2 query points per block (unchanged, proven) ----------------
__global__ __launch_bounds__(256,2) void mlp_kernel(
    const unsigned short* __restrict__ featT, // (B,N,C) bf16
    const int* __restrict__ sIdx,
    const unsigned short* __restrict__ sRotPk,// (B*P, S, 8) bf16 fragments
    const unsigned short* __restrict__ Wp1,   // [256][288] bf16
    const float* __restrict__ b1,
    const unsigned short* __restrict__ Wp2,   // [256][256] bf16
    const float* __restrict__ b2,
    float* __restrict__ out)
{
  __shared__ unsigned short Hlds[2][64*HST];
  const int bid = blockIdx.x;
  const int pp = (bid & 7) * 256 + (bid >> 3);  // XCD-chunked swizzle (2048 % 8 == 0)
  const int bp0 = pp*2, bp1 = bp0 + 1;
  const int b = bp0 >> 10, p0 = bp0 & 1023;
  const int t = threadIdx.x;
  const int w = t >> 6, l = t & 63;
  const int l15 = l & 15, q = l >> 4;

  unsigned rowOff[8];
  #pragma unroll
  for (int st=0; st<8; ++st){
    const int bpX = (st < 4) ? bp0 : bp1;
    const int s = (st & 3)*16 + l15;
    const int row = sIdx[(size_t)bpX*S_ + s];
    rowOff[st] = (unsigned)(((b*N_ + row)*C_ + q*8) * 2);
  }
  const char* fbase = (const char*)featT;

  f32x4 acc[4][8];
  #pragma unroll
  for (int at=0; at<4; ++at){
    const float4 bv = *(const float4*)(b1 + w*64 + at*16 + q*4);
    #pragma unroll
    for (int st=0; st<8; ++st){
      acc[at][st][0]=bv.x; acc[at][st][1]=bv.y; acc[at][st][2]=bv.z; acc[at][st][3]=bv.w;
    }
  }

  // ---- layer 1: K = 288 (8 feature K-steps + 1 rot/pad K-step) ----
  const unsigned short* wb1 = Wp1 + (size_t)(w*64 + l15)*288 + q*8;
  #pragma unroll
  for (int ks=0; ks<8; ++ks){
    short8 a[4], x[8];
    #pragma unroll
    for (int at=0; at<4; ++at) a[at] = *(const short8*)(wb1 + at*16*288 + ks*32);
    #pragma unroll
    for (int st=0; st<8; ++st) x[st] = *(const short8*)(fbase + rowOff[st] + ks*64);
    #pragma unroll
    for (int at=0; at<4; ++at)
      #pragma unroll
      for (int st=0; st<8; ++st)
        acc[at][st] = __builtin_amdgcn_mfma_f32_16x16x32_bf16(a[at], x[st], acc[at][st], 0,0,0);
  }
  { // K-step 8: k=256..258 are rot_d (prepacked bf16 fragments), k>=259 zero
    short8 a[4], x[8];
    #pragma unroll
    for (int at=0; at<4; ++at) a[at] = *(const short8*)(wb1 + at*16*288 + 8*32);
    #pragma unroll
    for (int st=0; st<8; ++st){
      short8 v = (short8){0,0,0,0,0,0,0,0};
      if (q == 0){
        const int bpX = (st < 4) ? bp0 : bp1;
        const int s = (st & 3)*16 + l15;
        v = *(const short8*)(sRotPk + ((size_t)bpX*S_ + s)*8);
      }
      x[st] = v;
    }
    #pragma unroll
    for (int at=0; at<4; ++at)
      #pragma unroll
      for (int st=0; st<8; ++st)
        acc[at][st] = __builtin_amdgcn_mfma_f32_16x16x32_bf16(a[at], x[st], acc[at][st], 0,0,0);
  }

  // ---- relu -> bf16 -> Hlds[p][s][o] ----
  #pragma unroll
  for (int at=0; at<4; ++at)
    #pragma unroll
    for (int st=0; st<8; ++st){
      const int s = (st & 3)*16 + l15;
      const int o = w*64 + at*16 + q*4;
      const unsigned h0 = f2bf(fmaxf(acc[at][st][0], 0.f));
      const unsigned h1 = f2bf(fmaxf(acc[at][st][1], 0.f));
      const unsigned h2 = f2bf(fmaxf(acc[at][st][2], 0.f));
      const unsigned h3 = f2bf(fmaxf(acc[at][st][3], 0.f));
      uint2 u; u.x = h0 | (h1 << 16); u.y = h2 | (h3 << 16);
      *(uint2*)&Hlds[st >> 2][s*HST + o] = u;
    }
  __syncthreads();

  // ---- layer 2: K = 256, B-frags from Hlds ----
  #pragma unroll
  for (int at=0; at<4; ++at){
    const float4 bv = *(const float4*)(b2 + w*64 + at*16 + q*4);
    #pragma unroll
    for (int st=0; st<8; ++st){
      acc[at][st][0]=bv.x; acc[at][st][1]=bv.y; acc[at][st][2]=bv.z; acc[at][st][3]=bv.w;
    }
  }
  const unsigned short* wb2 = Wp2 + (size_t)(w*64 + l15)*256 + q*8;
  #pragma unroll
  for (int ks=0; ks<8; ++ks){
    short8 a[4], h[8];
    #pragma unroll
    for (int at=0; at<4; ++at) a[at] = *(const short8*)(wb2 + at*16*256 + ks*32);
    #pragma unroll
    for (int st=0; st<8; ++st)
      h[st] = *(const short8*)&Hlds[st >> 2][((st & 3)*16 + l15)*HST + ks*32 + q*8];
    #pragma unroll
    for (int at=0; at<4; ++at)
      #pragma unroll
      for (int st=0; st<8; ++st)
        acc[at][st] = __builtin_amdgcn_mfma_f32_16x16x32_bf16(a[at], h[st], acc[at][st], 0,0,0);
  }

  // ---- max over s per p, relu, store ----
  #pragma unroll
  for (int g=0; g<2; ++g){
    const int p = p0 + g;
    #pragma unroll
    for (int at=0; at<4; ++at){
      #pragma unroll
      for (int r=0; r<4; ++r){
        float m = fmaxf(fmaxf(acc[at][g*4+0][r], acc[at][g*4+1][r]),
                        fmaxf(acc[at][g*4+2][r], acc[at][g*4+3][r]));
        m = fmaxf(m, __shfl_xor(m, 1, 64));
        m = fmaxf(m, __shfl_xor(m, 2, 64));
        m = fmaxf(m, __shfl_xor(m, 4, 64));
        m = fmaxf(m, __shfl_xor(m, 8, 64));
        m = fmaxf(m, 0.f);
        if (l15 == 0){
          const int o = w*64 + at*16 + q*4 + r;
          out[((size_t)b*256 + o)*P_ + p] = m;
        }
      }
    }
  }
}

extern "C" void kernel_launch(void* const* d_in, const int* in_sizes, int n_in,
                              void* d_out, int out_size, void* d_ws, size_t ws_size,
                              hipStream_t stream)
{
  const float* xyz  = (const float*)d_in[0];
  const float* feat = (const float*)d_in[1];
  const float* rot  = (const float*)d_in[2];
  const float* W1   = (const float*)d_in[3];
  const float* b1   = (const float*)d_in[4];
  const float* W2   = (const float*)d_in[5];
  const float* b2   = (const float*)d_in[6];
  float* out = (float*)d_out;

  char* ws = (char*)d_ws;
  unsigned short* featT = (unsigned short*)(ws);
  size_t off = (size_t)B_*N_*C_*2;                                        // 8.39 MB
  float* newXyz = (float*)(ws + off); off += (size_t)B_*P_*3*4;           // 48 KB
  int*   sIdx   = (int*)  (ws + off); off += (size_t)B_*P_*S_*4;          // 1 MB
  unsigned short* sRotPk = (unsigned short*)(ws + off); off += (size_t)B_*P_*S_*8*2; // 4 MB
  unsigned short* Wp1 = (unsigned short*)(ws + off); off += (size_t)256*288*2;
  unsigned short* Wp2 = (unsigned short*)(ws + off); off += (size_t)256*256*2;
  (void)ws_size; (void)in_sizes; (void)n_in; (void)out_size;

  hipLaunchKernelGGL(fps_kernel,    dim3(B_),                dim3(256),  0, stream, xyz, newXyz);
  hipLaunchKernelGGL(ftrans_kernel, dim3(N_/32, C_/32, B_),  dim3(256),  0, stream, feat, featT);
  hipLaunchKernelGGL(wprep_kernel,  dim3(256),               dim3(256),  0, stream, W1, W2, Wp1, Wp2);
  hipLaunchKernelGGL(query_kernel,  dim3(B_*P_/4),           dim3(256),  0, stream, xyz, rot, newXyz, sIdx, sRotPk);
  hipLaunchKernelGGL(mlp_kernel,    dim3(B_*P_/2),           dim3(256),  0, stream,
                     featT, sIdx, sRotPk, Wp1, b1, Wp2, b2, out);
}

// Round 9
// 782.320 us; speedup vs baseline: 1.1480x; 1.1480x over previous
//
#include <hip/hip_runtime.h>
#include <hip/hip_bf16.h>

#define B_ 4
#define N_ 4096
#define C_ 256
#define P_ 1024
#define S_ 64
#define HST 264   // H LDS k-stride (bf16 elems); 528B rows -> 2-way (free) frag reads

typedef __attribute__((ext_vector_type(8))) short short8;
typedef __attribute__((ext_vector_type(4))) float f32x4;

__device__ __forceinline__ float rn_mul(float a, float b){ return __fmul_rn(a,b); }
__device__ __forceinline__ float rn_add(float a, float b){ return __fadd_rn(a,b); }
__device__ __forceinline__ float rn_sub(float a, float b){ return __fsub_rn(a,b); }

__device__ __forceinline__ unsigned short f2bf(float x){ // RNE f32->bf16
  union { float f; unsigned u; } v; v.f = x;
  unsigned r = v.u + 0x7fffu + ((v.u >> 16) & 1u);
  return (unsigned short)(r >> 16);
}

// v_max with a DPP-permuted copy; OOB/disabled lanes contribute 0 (safe: dists >= 0)
#define DPPMAX(m, ctrl) \
  m = fmaxf(m, __int_as_float(__builtin_amdgcn_update_dpp(0, __float_as_int(m), ctrl, 0xF, 0xF, true)))

// ---------------- fused pre-kernel: fps (blocks 0..3) + wprep (4..259) + ftrans (260..4355) ----
// fps path is byte-exact the r4 657-us kernel. ftrans/wprep have no dependency on fps
// and run concurrently on other CUs, hidden inside the fps shadow.
__global__ __launch_bounds__(256, 1) void pre_kernel(
    const float* __restrict__ xyz, float* __restrict__ newXyz,
    const float* __restrict__ f, unsigned short* __restrict__ ft,
    const float* __restrict__ W1, const float* __restrict__ W2,
    unsigned short* __restrict__ Wp1, unsigned short* __restrict__ Wp2)
{
  __shared__ __align__(16) char shm[N_*3*4 + 8*16];
  const int gid = blockIdx.x;
  const int t = threadIdx.x;

  if (gid < B_){
    // ---------------- FPS: one block/batch, 4 waves x 16 pts (r4 exact) ----------------
    // Exact fp32 distance semantics (_rn chain, left-fold). First-occurrence argmax:
    // lane-local keep-first (strict >, ascending j) -> lowest lane of value-match ballot
    // (lanes own contiguous ascending ranges) -> ascending-wave keep-first scan.
    float* xl = (float*)shm;                      // 48 KB point store
    float4* cand = (float4*)(shm + N_*3*4);       // [2][4] double-buffered candidates
    const int b = gid;
    const int lane = t & 63, w = t >> 6;          // 4 waves
    const float* xb = xyz + (size_t)b*N_*3;
    {
      float4* dst = (float4*)xl; const float4* src = (const float4*)xb;
      for (int i = t; i < N_*3/4; i += 256) dst[i] = src[i];
    }
    __syncthreads();
    float px[16], py[16], pz[16], dist[16];
    {
      float buf[48];
      #pragma unroll
      for (int i=0;i<12;i++){
        const float4 v = *(const float4*)&xl[t*48 + i*4];
        buf[i*4+0]=v.x; buf[i*4+1]=v.y; buf[i*4+2]=v.z; buf[i*4+3]=v.w;
      }
      #pragma unroll
      for (int j=0;j<16;j++){
        px[j]=buf[j*3+0]; py[j]=buf[j*3+1]; pz[j]=buf[j*3+2];
        dist[j] = 1e10f;
      }
    }
    float cx = xl[0], cy = xl[1], cz = xl[2];     // farthest_0 = 0
    for (int it=0; it<P_; ++it){
      if (t == 0){
        float* nz = newXyz + ((size_t)b*P_ + it)*3;
        nz[0]=cx; nz[1]=cy; nz[2]=cz;
      }
      float bestv = -1.f; int bestj = 0;
      #pragma unroll
      for (int j=0;j<16;j++){
        const float dx = rn_sub(px[j],cx), dy = rn_sub(py[j],cy), dz = rn_sub(pz[j],cz);
        const float d  = rn_add(rn_add(rn_mul(dx,dx), rn_mul(dy,dy)), rn_mul(dz,dz));
        const float nd = fminf(dist[j], d);
        dist[j] = nd;
        if (nd > bestv){ bestv = nd; bestj = j; }   // strict > keeps first (lowest j)
      }
      // wave max of value only, via DPP (VALU pipe, no LDS)
      float m = bestv;
      DPPMAX(m, 0x111);  // row_shr:1
      DPPMAX(m, 0x112);  // row_shr:2
      DPPMAX(m, 0x114);  // row_shr:4
      DPPMAX(m, 0x118);  // row_shr:8
      DPPMAX(m, 0x142);  // row_bcast:15
      DPPMAX(m, 0x143);  // row_bcast:31
      const float ms = __int_as_float(__builtin_amdgcn_readlane(__float_as_int(m), 63));
      const unsigned long long bal = __ballot(bestv == ms);
      const int winlane = __ffsll((long long)bal) - 1;        // lowest lane = lowest index
      const int widx = __builtin_amdgcn_readlane(t*16 + bestj, winlane) & ~15;
      const int wj   = __builtin_amdgcn_readlane(bestj, winlane);
      const int pb = it & 1;                                   // double buffer (skew <= 1)
      if (lane == 0){
        const float* cp = xl + (size_t)(widx + wj)*3;
        cand[pb*4 + w] = make_float4(ms, cp[0], cp[1], cp[2]);
      }
      __syncthreads();
      // keep-first scan over 4 wave candidates (ascending wave id)
      const float4 c0 = cand[pb*4+0], c1 = cand[pb*4+1], c2 = cand[pb*4+2], c3 = cand[pb*4+3];
      float fv = c0.x; cx = c0.y; cy = c0.z; cz = c0.w;
      if (c1.x > fv){ fv = c1.x; cx = c1.y; cy = c1.z; cz = c1.w; }
      if (c2.x > fv){ fv = c2.x; cx = c2.y; cy = c2.z; cz = c2.w; }
      if (c3.x > fv){ fv = c3.x; cx = c3.y; cy = c3.z; cz = c3.w; }
    }
  } else if (gid < B_ + 256){
    // ---------------- weight prep: bf16, features-first permutation, zero pad ----------------
    const int o = gid - B_;
    Wp1[o*288 + t] = f2bf(W1[o*259 + 3 + t]);
    if (t < 32){
      float v = (t < 3) ? W1[o*259 + t] : 0.f;
      Wp1[o*288 + 256 + t] = f2bf(v);
    }
    Wp2[o*256 + t] = f2bf(W2[o*256 + t]);
  } else {
    // ---------------- feature transpose (B,C,N) f32 -> (B,N,C) bf16 ----------------
    const int idx = gid - (B_ + 256);
    const int nx = idx & 127;            // N_/32 = 128
    const int cyi = (idx >> 7) & 7;      // C_/32 = 8
    const int bz = idx >> 10;
    float (*tile)[33] = (float (*)[33])shm;
    const int n0 = nx*32, c0 = cyi*32;
    const int tx = t & 31, ty = t >> 5;  // 32x8
    #pragma unroll
    for (int j=0;j<4;j++)
      tile[ty + j*8][tx] = f[((size_t)bz*C_ + (size_t)(c0+ty+j*8))*N_ + n0 + tx];
    __syncthreads();
    #pragma unroll
    for (int j=0;j<4;j++)
      ft[((size_t)bz*N_ + (size_t)(n0+ty+j*8))*C_ + c0 + tx] = f2bf(tile[tx][ty + j*8]);
  }
}

// ---------------- cylinder query: one wave per (b,p); writes bf16 rot fragments ----------------
__global__ __launch_bounds__(256) void query_kernel(const float* __restrict__ xyz,
                                                    const float* __restrict__ rot,
                                                    const float* __restrict__ newXyz,
                                                    int* __restrict__ sIdx,
                                                    unsigned short* __restrict__ sRotPk)
{
  const int lane = threadIdx.x & 63;
  const int bp = blockIdx.x * 4 + (threadIdx.x >> 6);
  const int b = bp >> 10;
  const float* xb = xyz + (size_t)b*N_*3;
  const float* r9 = rot + (size_t)bp*9;
  const float R0=r9[0],R1=r9[1],R2=r9[2],R3=r9[3],R4=r9[4],R5=r9[5],R6=r9[6],R7=r9[7],R8=r9[8];
  const float nx=newXyz[bp*3+0], ny=newXyz[bp*3+1], nz=newXyz[bp*3+2];
  const float thr = R2;   // replicate the reference's r2-shadowing bug
  int* oI = sIdx + (size_t)bp*S_;
  unsigned short* oR = sRotPk + (size_t)bp*S_*8;
  int filled = 0;
  float p0r0=0.f, p0r1=0.f, p0r2=0.f;
  for (int base = 0; base < N_; base += 64){
    const int n = base + lane;
    const float dx = rn_sub(xb[n*3+0], nx);
    const float dy = rn_sub(xb[n*3+1], ny);
    const float dz = rn_sub(xb[n*3+2], nz);
    const float r0 = rn_add(rn_add(rn_mul(dx,R0), rn_mul(dy,R3)), rn_mul(dz,R6));
    const float r1 = rn_add(rn_add(rn_mul(dx,R1), rn_mul(dy,R4)), rn_mul(dz,R7));
    const float r2 = rn_add(rn_add(rn_mul(dx,R2), rn_mul(dy,R5)), rn_mul(dz,R8));
    if (base == 0){
      p0r0 = __shfl(r0, 0, 64); p0r1 = __shfl(r1, 0, 64); p0r2 = __shfl(r2, 0, 64);
    }
    const float d2 = rn_add(rn_mul(r1,r1), rn_mul(r2,r2));
    const bool m = (d2 < thr) & (r0 > -0.02f) & (r0 < 0.04f);
    const unsigned long long bal = __ballot(m);
    const int before = (int)__popcll(bal & ((1ull << lane) - 1ull));
    const int slot = filled + before;
    if (m && slot < S_){
      oI[slot] = n;
      uint4 u;
      u.x = (unsigned)f2bf(r0) | ((unsigned)f2bf(r1) << 16);
      u.y = (unsigned)f2bf(r2);
      u.z = 0u; u.w = 0u;
      *(uint4*)(oR + slot*8) = u;
    }
    filled += (int)__popcll(bal);
    if (filled >= S_) break;
  }
  if (filled < S_){
    const int slot = filled + lane;
    if (slot < S_){
      oI[slot] = 0;
      uint4 u;
      u.x = (unsigned)f2bf(p0r0) | ((unsigned)f2bf(p0r1) << 16);
      u.y = (unsigned)f2bf(p0r2);
      u.z = 0u; u.w = 0u;
      *(uint4*)(oR + slot*8) = u;
    }
  }
}

// ---------------- MFMA MLP: 2 query points per block (unchanged, proven) ----------------
__global__ __launch_bounds__(256,2) void mlp_kernel(
    const unsigned short* __restrict__ featT, // (B,N,C) bf16
    const int* __restrict__ sIdx,
    const unsigned short* __restrict__ sRotPk,// (B*P, S, 8) bf16 fragments
    const unsigned short* __restrict__ Wp1,   // [256][288] bf16
    const float* __restrict__ b1,
    const unsigned short* __restrict__ Wp2,   // [256][256] bf16
    const float* __restrict__ b2,
    float* __restrict__ out)
{
  __shared__ unsigned short Hlds[2][64*HST];
  const int bid = blockIdx.x;
  const int pp = (bid & 7) * 256 + (bid >> 3);  // XCD-chunked swizzle (2048 % 8 == 0)
  const int bp0 = pp*2, bp1 = bp0 + 1;
  const int b = bp0 >> 10, p0 = bp0 & 1023;
  const int t = threadIdx.x;
  const int w = t >> 6, l = t & 63;
  const int l15 = l & 15, q = l >> 4;

  unsigned rowOff[8];
  #pragma unroll
  for (int st=0; st<8; ++st){
    const int bpX = (st < 4) ? bp0 : bp1;
    const int s = (st & 3)*16 + l15;
    const int row = sIdx[(size_t)bpX*S_ + s];
    rowOff[st] = (unsigned)(((b*N_ + row)*C_ + q*8) * 2);
  }
  const char* fbase = (const char*)featT;

  f32x4 acc[4][8];
  #pragma unroll
  for (int at=0; at<4; ++at){
    const float4 bv = *(const float4*)(b1 + w*64 + at*16 + q*4);
    #pragma unroll
    for (int st=0; st<8; ++st){
      acc[at][st][0]=bv.x; acc[at][st][1]=bv.y; acc[at][st][2]=bv.z; acc[at][st][3]=bv.w;
    }
  }

  // ---- layer 1: K = 288 (8 feature K-steps + 1 rot/pad K-step) ----
  const unsigned short* wb1 = Wp1 + (size_t)(w*64 + l15)*288 + q*8;
  #pragma unroll
  for (int ks=0; ks<8; ++ks){
    short8 a[4], x[8];
    #pragma unroll
    for (int at=0; at<4; ++at) a[at] = *(const short8*)(wb1 + at*16*288 + ks*32);
    #pragma unroll
    for (int st=0; st<8; ++st) x[st] = *(const short8*)(fbase + rowOff[st] + ks*64);
    #pragma unroll
    for (int at=0; at<4; ++at)
      #pragma unroll
      for (int st=0; st<8; ++st)
        acc[at][st] = __builtin_amdgcn_mfma_f32_16x16x32_bf16(a[at], x[st], acc[at][st], 0,0,0);
  }
  { // K-step 8: k=256..258 are rot_d (prepacked bf16 fragments), k>=259 zero
    short8 a[4], x[8];
    #pragma unroll
    for (int at=0; at<4; ++at) a[at] = *(const short8*)(wb1 + at*16*288 + 8*32);
    #pragma unroll
    for (int st=0; st<8; ++st){
      short8 v = (short8){0,0,0,0,0,0,0,0};
      if (q == 0){
        const int bpX = (st < 4) ? bp0 : bp1;
        const int s = (st & 3)*16 + l15;
        v = *(const short8*)(sRotPk + ((size_t)bpX*S_ + s)*8);
      }
      x[st] = v;
    }
    #pragma unroll
    for (int at=0; at<4; ++at)
      #pragma unroll
      for (int st=0; st<8; ++st)
        acc[at][st] = __builtin_amdgcn_mfma_f32_16x16x32_bf16(a[at], x[st], acc[at][st], 0,0,0);
  }

  // ---- relu -> bf16 -> Hlds[p][s][o] ----
  #pragma unroll
  for (int at=0; at<4; ++at)
    #pragma unroll
    for (int st=0; st<8; ++st){
      const int s = (st & 3)*16 + l15;
      const int o = w*64 + at*16 + q*4;
      const unsigned h0 = f2bf(fmaxf(acc[at][st][0], 0.f));
      const unsigned h1 = f2bf(fmaxf(acc[at][st][1], 0.f));
      const unsigned h2 = f2bf(fmaxf(acc[at][st][2], 0.f));
      const unsigned h3 = f2bf(fmaxf(acc[at][st][3], 0.f));
      uint2 u; u.x = h0 | (h1 << 16); u.y = h2 | (h3 << 16);
      *(uint2*)&Hlds[st >> 2][s*HST + o] = u;
    }
  __syncthreads();

  // ---- layer 2: K = 256, B-frags from Hlds ----
  #pragma unroll
  for (int at=0; at<4; ++at){
    const float4 bv = *(const float4*)(b2 + w*64 + at*16 + q*4);
    #pragma unroll
    for (int st=0; st<8; ++st){
      acc[at][st][0]=bv.x; acc[at][st][1]=bv.y; acc[at][st][2]=bv.z; acc[at][st][3]=bv.w;
    }
  }
  const unsigned short* wb2 = Wp2 + (size_t)(w*64 + l15)*256 + q*8;
  #pragma unroll
  for (int ks=0; ks<8; ++ks){
    short8 a[4], h[8];
    #pragma unroll
    for (int at=0; at<4; ++at) a[at] = *(const short8*)(wb2 + at*16*256 + ks*32);
    #pragma unroll
    for (int st=0; st<8; ++st)
      h[st] = *(const short8*)&Hlds[st >> 2][((st & 3)*16 + l15)*HST + ks*32 + q*8];
    #pragma unroll
    for (int at=0; at<4; ++at)
      #pragma unroll
      for (int st=0; st<8; ++st)
        acc[at][st] = __builtin_amdgcn_mfma_f32_16x16x32_bf16(a[at], h[st], acc[at][st], 0,0,0);
  }

  // ---- max over s per p, relu, store ----
  #pragma unroll
  for (int g=0; g<2; ++g){
    const int p = p0 + g;
    #pragma unroll
    for (int at=0; at<4; ++at){
      #pragma unroll
      for (int r=0; r<4; ++r){
        float m = fmaxf(fmaxf(acc[at][g*4+0][r], acc[at][g*4+1][r]),
                        fmaxf(acc[at][g*4+2][r], acc[at][g*4+3][r]));
        m = fmaxf(m, __shfl_xor(m, 1, 64));
        m = fmaxf(m, __shfl_xor(m, 2, 64));
        m = fmaxf(m, __shfl_xor(m, 4, 64));
        m = fmaxf(m, __shfl_xor(m, 8, 64));
        m = fmaxf(m, 0.f);
        if (l15 == 0){
          const int o = w*64 + at*16 + q*4 + r;
          out[((size_t)b*256 + o)*P_ + p] = m;
        }
      }
    }
  }
}

extern "C" void kernel_launch(void* const* d_in, const int* in_sizes, int n_in,
                              void* d_out, int out_size, void* d_ws, size_t ws_size,
                              hipStream_t stream)
{
  const float* xyz  = (const float*)d_in[0];
  const float* feat = (const float*)d_in[1];
  const float* rot  = (const float*)d_in[2];
  const float* W1   = (const float*)d_in[3];
  const float* b1   = (const float*)d_in[4];
  const float* W2   = (const float*)d_in[5];
  const float* b2   = (const float*)d_in[6];
  float* out = (float*)d_out;

  char* ws = (char*)d_ws;
  unsigned short* featT = (unsigned short*)(ws);
  size_t off = (size_t)B_*N_*C_*2;                                        // 8.39 MB
  float* newXyz = (float*)(ws + off); off += (size_t)B_*P_*3*4;           // 48 KB
  int*   sIdx   = (int*)  (ws + off); off += (size_t)B_*P_*S_*4;          // 1 MB
  unsigned short* sRotPk = (unsigned short*)(ws + off); off += (size_t)B_*P_*S_*8*2; // 4 MB
  unsigned short* Wp1 = (unsigned short*)(ws + off); off += (size_t)256*288*2;
  unsigned short* Wp2 = (unsigned short*)(ws + off); off += (size_t)256*256*2;
  (void)ws_size; (void)in_sizes; (void)n_in; (void)out_size;

  // fused: fps (4 blocks) + wprep (256 blocks) + ftrans (4096 blocks)
  hipLaunchKernelGGL(pre_kernel,   dim3(B_ + 256 + 4096), dim3(256), 0, stream,
                     xyz, newXyz, feat, featT, W1, W2, Wp1, Wp2);
  hipLaunchKernelGGL(query_kernel, dim3(B_*P_/4),         dim3(256), 0, stream,
                     xyz, rot, newXyz, sIdx, sRotPk);
  hipLaunchKernelGGL(mlp_kernel,   dim3(B_*P_/2),         dim3(256), 0, stream,
                     featT, sIdx, sRotPk, Wp1, b1, Wp2, b2, out);
}